// Round 11
// baseline (196.213 us; speedup 1.0000x reference)
//
#include <hip/hip_runtime.h>
#include <hip/hip_bf16.h>
#include <float.h>

#define B_ 8
#define N_ 8192
#define M_ 2048
#define CC_ 256
#define CP_ 128
#define CIN_ 384
#define GRP_ 8
#define BN_ (B_ * N_)

typedef __attribute__((ext_vector_type(8))) short short8;
typedef __attribute__((ext_vector_type(4))) short short4v;
typedef __attribute__((ext_vector_type(4))) float f32x4;

static __device__ __forceinline__ float bf2f(unsigned short u) {
  union { unsigned int i; float f; } v; v.i = ((unsigned int)u) << 16; return v.f;
}
static __device__ __forceinline__ unsigned short f2bf(float f) {
  union { float f; unsigned int i; } v; v.f = f;
  unsigned int u = v.i;
  unsigned int r = (u + 0x7FFFu + ((u >> 16) & 1u)) >> 16;
  return (unsigned short)r;
}
static __device__ __forceinline__ void gload16(const void* g, void* l) {
  __builtin_amdgcn_global_load_lds(
      (const __attribute__((address_space(1))) void*)g,
      (__attribute__((address_space(3))) void*)l, 16, 0, 0);
}

// ---------------- fused front: knn (512 blocks, 32KB LDS via mk-overlay) + wcast + transpose + tail
// blocks [0,512): knn | [512,704): wcast | [704,6848): transpose tiles (2/blk, 12288 tiles) | [6848,7360): tail
__global__ __launch_bounds__(512) void k_front(
    const float* __restrict__ pc, const float* __restrict__ cc,
    int* __restrict__ idx, float* __restrict__ wts,
    const float* __restrict__ W1, const float* __restrict__ W2,
    short* __restrict__ W1b, short* __restrict__ W2b,
    const float* __restrict__ cf, short* __restrict__ FT,
    const float* __restrict__ pf, short* __restrict__ x0T,
    const float* __restrict__ te, float* __restrict__ out) {
  __shared__ __align__(16) char smem[32768];
  int bid = blockIdx.x;
  int t = threadIdx.x;
  if (bid < 512) {
    // ---- 3-NN: 8 waves, 8-way M-chunks, 2 pts/thread, f64 packed keys (exact) ----
    float4* ctr = (float4*)smem;                          // 32 KB
    double (*mk)[3][128] = (double(*)[3][128])smem;       // 24 KB, overlaid after loop
    int b = bid >> 6;
    int base = (bid & 63) * 128;
    const float* ccb = cc + (size_t)b * 3 * M_;
    for (int i = t; i < M_; i += 512) {
      float x = ccb[i], y = ccb[M_ + i], z = ccb[2 * M_ + i];
      ctr[i] = make_float4(x, y, z, x * x + y * y + z * z);
    }
    __syncthreads();
    int wv = t >> 6, lane = t & 63;
    const float* pcb = pc + (size_t)b * 3 * N_;
    int na = base + lane, nb = base + 64 + lane;
    float pxa = pcb[na], pya = pcb[N_ + na], pza = pcb[2 * N_ + na];
    float pxb = pcb[nb], pyb = pcb[N_ + nb], pzb = pcb[2 * N_ + nb];
    float p2a = pxa * pxa + pya * pya + pza * pza;
    float p2b = pxb * pxb + pyb * pyb + pzb * pzb;
    const double kinit = __hiloint2double(0x7F7FFFFF, 0);
    double a0 = kinit, a1 = kinit, a2 = kinit;
    double e0 = kinit, e1 = kinit, e2 = kinit;
    const float4* C = ctr + wv * 256;
    int mbase = wv * 256;
#pragma unroll 8
    for (int m = 0; m < 256; ++m) {
      float4 c = C[m];                           // wave-uniform -> LDS broadcast
      float dota = pxa * c.x;
      dota = __builtin_fmaf(pya, c.y, dota);
      dota = __builtin_fmaf(pza, c.z, dota);
      float da = __builtin_fmaf(-2.f, dota, c.w) + p2a;
      float dotb = pxb * c.x;
      dotb = __builtin_fmaf(pyb, c.y, dotb);
      dotb = __builtin_fmaf(pzb, c.z, dotb);
      float db = __builtin_fmaf(-2.f, dotb, c.w) + p2b;
      double ka = __hiloint2double(__float_as_int(da), mbase + m);
      double kb = __hiloint2double(__float_as_int(db), mbase + m);
      double t0 = fmin(ka, a0);
      double t1 = fmin(fmax(ka, a0), a1);
      double t2 = fmin(fmax(ka, a1), a2);
      a0 = t0; a1 = t1; a2 = t2;
      double u0 = fmin(kb, e0);
      double u1 = fmin(fmax(kb, e0), e1);
      double u2 = fmin(fmax(kb, e1), e2);
      e0 = u0; e1 = u1; e2 = u2;
    }
    __syncthreads();   // all waves done reading ctr before mk overlay write
    mk[wv][0][lane] = a0; mk[wv][1][lane] = a1; mk[wv][2][lane] = a2;
    mk[wv][0][64 + lane] = e0; mk[wv][1][64 + lane] = e1; mk[wv][2][64 + lane] = e2;
    __syncthreads();
    if (t < 128) {
      double k0 = kinit, k1 = kinit, k2 = kinit;
#pragma unroll
      for (int w = 0; w < 8; ++w) {
#pragma unroll
        for (int j = 0; j < 3; ++j) {
          double key = mk[w][j][t];
          double n0 = fmin(key, k0);
          double n1 = fmin(fmax(key, k0), k1);
          double n2 = fmin(fmax(key, k1), k2);
          k0 = n0; k1 = n1; k2 = n2;
        }
      }
      float d0 = __int_as_float(__double2hiint(k0));
      float d1 = __int_as_float(__double2hiint(k1));
      float d2 = __int_as_float(__double2hiint(k2));
      float w0 = 1.f / (d0 + 1e-8f), w1 = 1.f / (d1 + 1e-8f), w2 = 1.f / (d2 + 1e-8f);
      float inv = 1.f / (w0 + w1 + w2);
      int bn = b * N_ + base + t;
      wts[bn] = w0 * inv; wts[BN_ + bn] = w1 * inv; wts[2 * BN_ + bn] = w2 * inv;
      idx[bn] = __double2loint(k0);
      idx[BN_ + bn] = __double2loint(k1);
      idx[2 * BN_ + bn] = __double2loint(k2);
    }
  } else if (bid < 704) {
    // ---- weight cast ----
    int i = (bid - 512) * 512 + t;
    if (i < 256 * CIN_) W1b[i] = (short)f2bf(W1[i]);
    if (i < 256 * 256)  W2b[i] = (short)f2bf(W2[i]);
  } else if (bid < 6848) {
    // ---- transpose+cast, two 32x32 tiles per block (12288 tiles total) ----
    int q2 = (bid - 704) * 2 + (t >> 8);
    int tt = t & 255;
    float (*tile)[33] = (float(*)[33])(smem + (t >> 8) * 4352);
    const float* in; short* outp;
    int C, Nn, RS, coff, n0, c0, b;
    if (q2 < 4096) {
      in = cf; outp = FT; C = CC_; Nn = M_; RS = CC_; coff = 0;
      n0 = (q2 & 63) * 32; c0 = ((q2 >> 6) & 7) * 32; b = q2 >> 9;
    } else {
      int q = q2 - 4096;
      in = pf; outp = x0T; C = CP_; Nn = N_; RS = CP_; coff = 0;
      n0 = (q & 255) * 32; c0 = ((q >> 8) & 3) * 32; b = q >> 10;
    }
    const float* inb = in + (size_t)b * C * Nn;
    short* outb = outp + (size_t)b * Nn * RS;
    int tx = tt & 31, ty = tt >> 5;
#pragma unroll
    for (int i = 0; i < 32; i += 8)
      tile[ty + i][tx] = inb[(size_t)(c0 + ty + i) * Nn + n0 + tx];
    __syncthreads();
#pragma unroll
    for (int i = 0; i < 32; i += 8)
      outb[(size_t)(n0 + ty + i) * RS + coff + c0 + tx] = (short)f2bf(tile[tx][ty + i]);
  } else {
    // ---- tail: coords copy + time_emb broadcast ----
    int total = 196608 + B_ * 64 * N_;
    for (int i = (bid - 6848) * 512 + t; i < total; i += 512 * 512) {
      if (i < 196608) {
        out[16777216 + i] = pc[i];
      } else {
        int j = i - 196608;
        int bd = j >> 13;
        out[16973824 + j] = te[bd];
      }
    }
  }
}

// ---------------- bf16 MFMA GEMM, 3 modes ----------------
// MODE 0: plain store (G-GEMM, no bias/stats)
// MODE 1: bias + GN partial stats (gemm2)
// MODE 2: bias + GN stats + interp-gather from G: v += sum_k w_k * G[i_k][o] (gemm1)
// Y[b][n][o] = W[o][:] . X[b][n][:] (+ bias + gather); W row stride ldw, X row stride K.
template <int MODE>
__global__ __launch_bounds__(256) void k_gemm(
    const short* __restrict__ Wb, int ldw,
    const short* __restrict__ Xb, int nrows,
    const float* __restrict__ bias, short* __restrict__ Yb,
    float* __restrict__ part, int K,
    const short* __restrict__ G, const int* __restrict__ idx,
    const float* __restrict__ wts) {
  __shared__ __align__(16) short sW[128 * 64];   // 16 KB
  __shared__ __align__(16) short sX[128 * 64];   // 16 KB
  int b = blockIdx.z;
  int otile = blockIdx.x * 128;
  int ntile = blockIdx.y * 128;
  int t = threadIdx.x;
  int wv = t >> 6, lane = t & 63;
  int wr = wv >> 1, wc = wv & 1;
  int fr = lane & 15;     // fragment row
  int g = lane >> 4;      // k-subchunk selector
  f32x4 acc[4][4] = {};
  const short* Wp = Wb + (size_t)otile * ldw;
  const short* Xp = Xb + ((size_t)b * nrows + ntile) * K;
  for (int k0 = 0; k0 < K; k0 += 64) {
#pragma unroll
    for (int j = 0; j < 4; ++j) {
      int s = j * 256 + t;          // slot 0..1023, 16B each
      int row = s >> 3;             // 8 slots (128B) per row
      int kc = (s & 7) ^ (row & 7); // inverse-swizzled source chunk
      gload16(Wp + (size_t)row * ldw + k0 + kc * 8, sW + j * 2048 + wv * 512);
      gload16(Xp + (size_t)row * K + k0 + kc * 8, sX + j * 2048 + wv * 512);
    }
    __syncthreads();
#pragma unroll
    for (int h = 0; h < 2; ++h) {
      short8 af[4], bfr[4];
#pragma unroll
      for (int m = 0; m < 4; ++m) {
        int ra = wr * 64 + m * 16 + fr;
        af[m] = *(const short8*)(sW + ra * 64 + (((h * 4 + g) ^ (ra & 7)) << 3));
        int rb = wc * 64 + m * 16 + fr;
        bfr[m] = *(const short8*)(sX + rb * 64 + (((h * 4 + g) ^ (rb & 7)) << 3));
      }
#pragma unroll
      for (int m = 0; m < 4; ++m)
#pragma unroll
        for (int nn = 0; nn < 4; ++nn)
          acc[m][nn] = __builtin_amdgcn_mfma_f32_16x16x32_bf16(af[m], bfr[nn], acc[m][nn], 0, 0, 0);
    }
    __syncthreads();
  }
  // epilogue
  int ib0[4], ib1[4], ib2[4];
  float wt0[4], wt1[4], wt2[4];
  if constexpr (MODE == 2) {
#pragma unroll
    for (int nn = 0; nn < 4; ++nn) {
      int n = ntile + wc * 64 + nn * 16 + fr;
      int bn = b * N_ + n;
      ib0[nn] = idx[bn]; ib1[nn] = idx[BN_ + bn]; ib2[nn] = idx[2 * BN_ + bn];
      wt0[nn] = wts[bn]; wt1[nn] = wts[BN_ + bn]; wt2[nn] = wts[2 * BN_ + bn];
    }
  }
  float s01 = 0.f, ss01 = 0.f, s23 = 0.f, ss23 = 0.f;
#pragma unroll
  for (int m = 0; m < 4; ++m) {
    int o = otile + wr * 64 + m * 16 + g * 4;
    float4 bi = make_float4(0.f, 0.f, 0.f, 0.f);
    if constexpr (MODE != 0) bi = *(const float4*)(bias + o);
#pragma unroll
    for (int nn = 0; nn < 4; ++nn) {
      int n = ntile + wc * 64 + nn * 16 + fr;
      float v0 = acc[m][nn][0] + bi.x;
      float v1 = acc[m][nn][1] + bi.y;
      float v2 = acc[m][nn][2] + bi.z;
      float v3 = acc[m][nn][3] + bi.w;
      if constexpr (MODE == 2) {
        const short* Gb = G + (size_t)b * M_ * 256 + o;
        short4v g0 = *(const short4v*)(Gb + (size_t)ib0[nn] * 256);
        short4v g1 = *(const short4v*)(Gb + (size_t)ib1[nn] * 256);
        short4v g2 = *(const short4v*)(Gb + (size_t)ib2[nn] * 256);
        v0 += wt0[nn] * bf2f((unsigned short)g0[0]) + wt1[nn] * bf2f((unsigned short)g1[0]) + wt2[nn] * bf2f((unsigned short)g2[0]);
        v1 += wt0[nn] * bf2f((unsigned short)g0[1]) + wt1[nn] * bf2f((unsigned short)g1[1]) + wt2[nn] * bf2f((unsigned short)g2[1]);
        v2 += wt0[nn] * bf2f((unsigned short)g0[2]) + wt1[nn] * bf2f((unsigned short)g1[2]) + wt2[nn] * bf2f((unsigned short)g2[2]);
        v3 += wt0[nn] * bf2f((unsigned short)g0[3]) + wt1[nn] * bf2f((unsigned short)g1[3]) + wt2[nn] * bf2f((unsigned short)g2[3]);
      }
      if constexpr (MODE != 0) {
        if (m < 2) { s01 += v0 + v1 + v2 + v3; ss01 += v0*v0 + v1*v1 + v2*v2 + v3*v3; }
        else       { s23 += v0 + v1 + v2 + v3; ss23 += v0*v0 + v1*v1 + v2*v2 + v3*v3; }
      }
      short4v sv;
      sv[0] = (short)f2bf(v0);
      sv[1] = (short)f2bf(v1);
      sv[2] = (short)f2bf(v2);
      sv[3] = (short)f2bf(v3);
      *(short4v*)(Yb + ((size_t)b * nrows + n) * 256 + o) = sv;
    }
  }
  if constexpr (MODE != 0) {
#pragma unroll
    for (int off = 32; off > 0; off >>= 1) {
      s01 += __shfl_down(s01, off);
      ss01 += __shfl_down(ss01, off);
      s23 += __shfl_down(s23, off);
      ss23 += __shfl_down(ss23, off);
    }
    float* wred = (float*)sW;   // LDS reuse (k-loop done, post-barrier)
    if (lane == 0) {
      wred[wv * 4 + 0] = s01; wred[wv * 4 + 1] = ss01;
      wred[wv * 4 + 2] = s23; wred[wv * 4 + 3] = ss23;
    }
    __syncthreads();
    if (t < 8) {
      int gl = t >> 1, sel = t & 1;                 // local group 0..3, sum/sumsq
      int wrn = gl >> 1;                            // which wr produced it
      int id = (gl & 1) * 2 + sel;                  // s01/ss01 vs s23/ss23
      float v = wred[(wrn * 2 + 0) * 4 + id] + wred[(wrn * 2 + 1) * 4 + id];
      part[(((size_t)b * 8 + blockIdx.x * 4 + gl) * 64 + blockIdx.y) * 2 + sel] = v;
    }
  }
}

// ---------------- GN + swish in place (bf16 [b][n][256]), stats finalized in-block ----
__global__ __launch_bounds__(256) void k_gnapply(short* __restrict__ Y,
                                                 const float* __restrict__ part,
                                                 const float* __restrict__ gw,
                                                 const float* __restrict__ gb) {
  __shared__ float fs[128];
  int t = threadIdx.x;
  if (t < 64) {
    float s = 0.f, ss = 0.f;
    for (int j = 0; j < 64; ++j) {
      s += part[((size_t)t * 64 + j) * 2];
      ss += part[((size_t)t * 64 + j) * 2 + 1];
    }
    const float cnt = 32.f * 8192.f;
    float mean = s / cnt;
    float var = ss / cnt - mean * mean;
    fs[t * 2] = mean;
    fs[t * 2 + 1] = rsqrtf(var + 1e-5f);
  }
  __syncthreads();
  unsigned int* Yd = (unsigned int*)Y;
  int total = B_ * N_ * 128;
  for (int i = blockIdx.x * blockDim.x + t; i < total;
       i += gridDim.x * blockDim.x) {
    int o2 = i & 127;
    int b = i >> 20;
    int g = o2 >> 4;
    float mean = fs[(b * 8 + g) * 2], rstd = fs[(b * 8 + g) * 2 + 1];
    unsigned int v = Yd[i];
    int o = o2 * 2;
    float a = bf2f((unsigned short)(v & 0xFFFF));
    float c = bf2f((unsigned short)(v >> 16));
    a = (a - mean) * rstd * gw[o] + gb[o];
    c = (c - mean) * rstd * gw[o + 1] + gb[o + 1];
    a = a / (1.f + __expf(-a));
    c = c / (1.f + __expf(-c));
    Yd[i] = (unsigned int)f2bf(a) | ((unsigned int)f2bf(c) << 16);
  }
}

// ---------------- GN + swish + transpose -> out [b][o][n] f32, stats in-block ----------
__global__ __launch_bounds__(256) void k_gnapply_out(
    const short* __restrict__ Y, const float* __restrict__ part,
    const float* __restrict__ gw, const float* __restrict__ gb,
    float* __restrict__ out) {
  __shared__ float tile[64][65];
  __shared__ float fs[16];
  int b = blockIdx.z;
  int t = threadIdx.x;
  if (t < 8) {
    float s = 0.f, ss = 0.f;
    for (int j = 0; j < 64; ++j) {
      s += part[(((size_t)b * 8 + t) * 64 + j) * 2];
      ss += part[(((size_t)b * 8 + t) * 64 + j) * 2 + 1];
    }
    const float cnt = 32.f * 8192.f;
    float mean = s / cnt;
    float var = ss / cnt - mean * mean;
    fs[t * 2] = mean;
    fs[t * 2 + 1] = rsqrtf(var + 1e-5f);
  }
  __syncthreads();
  int n0 = blockIdx.x * 64, o0 = blockIdx.y * 64;
  int row = t >> 5, dcol = t & 31;
  const unsigned int* Yd = (const unsigned int*)(Y + (size_t)b * N_ * 256);
  int o = o0 + dcol * 2;
  int g = o >> 5;
  float mean = fs[g * 2], rstd = fs[g * 2 + 1];
  float w0 = gw[o], w1 = gw[o + 1], bb0 = gb[o], bb1 = gb[o + 1];
#pragma unroll
  for (int p = 0; p < 8; ++p) {
    int n = n0 + p * 8 + row;
    unsigned int v = Yd[(size_t)n * 128 + (o0 >> 1) + dcol];
    float a = bf2f((unsigned short)(v & 0xFFFF));
    float c = bf2f((unsigned short)(v >> 16));
    a = (a - mean) * rstd * w0 + bb0; a = a / (1.f + __expf(-a));
    c = (c - mean) * rstd * w1 + bb1; c = c / (1.f + __expf(-c));
    tile[p * 8 + row][dcol * 2] = a;
    tile[p * 8 + row][dcol * 2 + 1] = c;
  }
  __syncthreads();
  int ol = t >> 2, nch = (t & 3) * 16;
  float* ob = out + ((size_t)(b * 256 + o0 + ol)) * N_ + n0 + nch;
#pragma unroll
  for (int c4 = 0; c4 < 16; c4 += 4) {
    float4 v4;
    v4.x = tile[nch + c4 + 0][ol];
    v4.y = tile[nch + c4 + 1][ol];
    v4.z = tile[nch + c4 + 2][ol];
    v4.w = tile[nch + c4 + 3][ol];
    *(float4*)(ob + c4) = v4;
  }
}

extern "C" void kernel_launch(void* const* d_in, const int* in_sizes, int n_in,
                              void* d_out, int out_size, void* d_ws, size_t ws_size,
                              hipStream_t stream) {
  const float* pc  = (const float*)d_in[0];
  const float* cc  = (const float*)d_in[1];
  const float* cf  = (const float*)d_in[2];
  const float* pf  = (const float*)d_in[3];
  const float* te  = (const float*)d_in[4];
  const float* W1  = (const float*)d_in[5];
  const float* b1  = (const float*)d_in[6];
  const float* g1w = (const float*)d_in[7];
  const float* g1b = (const float*)d_in[8];
  const float* W2  = (const float*)d_in[9];
  const float* b2  = (const float*)d_in[10];
  const float* g2w = (const float*)d_in[11];
  const float* g2b = (const float*)d_in[12];
  float* out = (float*)d_out;

  char* ws = (char*)d_ws;
  // Overlay region [0, 33.6MB): FT | G | x0T during phase 1-3; y2 (gemm2 out) afterwards.
  short* FT  = (short*)ws;                                   // 8 MiB (8*2048*256*2)
  short* G   = (short*)(ws + 8388608);                       // 8 MiB
  short* x0T = (short*)(ws + 16777216);                      // 16 MiB (8*8192*128*2)
  short* y2  = (short*)ws;                                   // 32 MiB, overlays all three
  size_t off = 33554432;
  auto alloc = [&](size_t bytes) {
    char* p = ws + off;
    off += (bytes + 255) & ~(size_t)255;
    return p;
  };
  short* y1   = (short*)alloc((size_t)B_ * N_ * 256 * 2);    // 32 MiB
  short* W1b  = (short*)alloc(256 * 384 * 2);
  short* W2b  = (short*)alloc(256 * 256 * 2);
  int*   idx  = (int*)alloc((size_t)3 * BN_ * 4);
  float* wts  = (float*)alloc((size_t)3 * BN_ * 4);
  float* part1 = (float*)alloc(8 * 8 * 64 * 2 * 4);
  float* part2 = (float*)alloc(8 * 8 * 64 * 2 * 4);

  k_front<<<7360, 512, 0, stream>>>(pc, cc, idx, wts, W1, W2, W1b, W2b,
                                    cf, FT, pf, x0T, te, out);
  // G[b][m][o] = FT[b][m][:256] . W1[o][:256]
  k_gemm<0><<<dim3(2, M_ / 128, B_), 256, 0, stream>>>(
      W1b, CIN_, FT, M_, nullptr, G, nullptr, 256, nullptr, nullptr, nullptr);
  // y1[b][n][o] = pf-part GEMM (K=128) + gather(G) + bias, with GN stats
  k_gemm<2><<<dim3(2, N_ / 128, B_), 256, 0, stream>>>(
      W1b + 256, CIN_, x0T, N_, b1, y1, part1, CP_, G, idx, wts);
  k_gnapply<<<2048, 256, 0, stream>>>(y1, part1, g1w, g1b);
  k_gemm<1><<<dim3(2, N_ / 128, B_), 256, 0, stream>>>(
      W2b, 256, y1, N_, b2, y2, part2, 256, nullptr, nullptr, nullptr);
  k_gnapply_out<<<dim3(N_ / 64, 4, B_), 256, 0, stream>>>(y2, part2, g2w, g2b, out);
}

// Round 12
// 179.851 us; speedup vs baseline: 1.0910x; 1.0910x over previous
//
#include <hip/hip_runtime.h>
#include <hip/hip_bf16.h>
#include <float.h>

#define B_ 8
#define N_ 8192
#define M_ 2048
#define CC_ 256
#define CP_ 128
#define CIN_ 384
#define GRP_ 8
#define BN_ (B_ * N_)

typedef __attribute__((ext_vector_type(8))) short short8;
typedef __attribute__((ext_vector_type(4))) short short4v;
typedef __attribute__((ext_vector_type(4))) float f32x4;

static __device__ __forceinline__ float bf2f(unsigned short u) {
  union { unsigned int i; float f; } v; v.i = ((unsigned int)u) << 16; return v.f;
}
static __device__ __forceinline__ unsigned short f2bf(float f) {
  union { float f; unsigned int i; } v; v.f = f;
  unsigned int u = v.i;
  unsigned int r = (u + 0x7FFFu + ((u >> 16) & 1u)) >> 16;
  return (unsigned short)r;
}
static __device__ __forceinline__ void gload16(const void* g, void* l) {
  __builtin_amdgcn_global_load_lds(
      (const __attribute__((address_space(1))) void*)g,
      (__attribute__((address_space(3))) void*)l, 16, 0, 0);
}

// ---------------- fused front: knn (512 blocks, 32KB LDS via mk-overlay) + wcast + transpose + tail
// blocks [0,512): knn | [512,704): wcast | [704,6848): transpose tiles (2/blk, 12288 tiles) | [6848,7360): tail
__global__ __launch_bounds__(512) void k_front(
    const float* __restrict__ pc, const float* __restrict__ cc,
    int* __restrict__ idx, float* __restrict__ wts,
    const float* __restrict__ W1, const float* __restrict__ W2,
    short* __restrict__ W1b, short* __restrict__ W2b,
    const float* __restrict__ cf, short* __restrict__ FT,
    const float* __restrict__ pf, short* __restrict__ x0T,
    const float* __restrict__ te, float* __restrict__ out) {
  __shared__ __align__(16) char smem[32768];
  int bid = blockIdx.x;
  int t = threadIdx.x;
  if (bid < 512) {
    // ---- 3-NN: 8 waves, 8-way M-chunks, 2 pts/thread, f64 packed keys (exact) ----
    float4* ctr = (float4*)smem;                          // 32 KB
    double (*mk)[3][128] = (double(*)[3][128])smem;       // 24 KB, overlaid after loop
    int b = bid >> 6;
    int base = (bid & 63) * 128;
    const float* ccb = cc + (size_t)b * 3 * M_;
    for (int i = t; i < M_; i += 512) {
      float x = ccb[i], y = ccb[M_ + i], z = ccb[2 * M_ + i];
      ctr[i] = make_float4(x, y, z, x * x + y * y + z * z);
    }
    __syncthreads();
    int wv = t >> 6, lane = t & 63;
    const float* pcb = pc + (size_t)b * 3 * N_;
    int na = base + lane, nb = base + 64 + lane;
    float pxa = pcb[na], pya = pcb[N_ + na], pza = pcb[2 * N_ + na];
    float pxb = pcb[nb], pyb = pcb[N_ + nb], pzb = pcb[2 * N_ + nb];
    float p2a = pxa * pxa + pya * pya + pza * pza;
    float p2b = pxb * pxb + pyb * pyb + pzb * pzb;
    const double kinit = __hiloint2double(0x7F7FFFFF, 0);
    double a0 = kinit, a1 = kinit, a2 = kinit;
    double e0 = kinit, e1 = kinit, e2 = kinit;
    const float4* C = ctr + wv * 256;
    int mbase = wv * 256;
#pragma unroll 8
    for (int m = 0; m < 256; ++m) {
      float4 c = C[m];                           // wave-uniform -> LDS broadcast
      float dota = pxa * c.x;
      dota = __builtin_fmaf(pya, c.y, dota);
      dota = __builtin_fmaf(pza, c.z, dota);
      float da = __builtin_fmaf(-2.f, dota, c.w) + p2a;
      float dotb = pxb * c.x;
      dotb = __builtin_fmaf(pyb, c.y, dotb);
      dotb = __builtin_fmaf(pzb, c.z, dotb);
      float db = __builtin_fmaf(-2.f, dotb, c.w) + p2b;
      double ka = __hiloint2double(__float_as_int(da), mbase + m);
      double kb = __hiloint2double(__float_as_int(db), mbase + m);
      double t0 = fmin(ka, a0);
      double t1 = fmin(fmax(ka, a0), a1);
      double t2 = fmin(fmax(ka, a1), a2);
      a0 = t0; a1 = t1; a2 = t2;
      double u0 = fmin(kb, e0);
      double u1 = fmin(fmax(kb, e0), e1);
      double u2 = fmin(fmax(kb, e1), e2);
      e0 = u0; e1 = u1; e2 = u2;
    }
    __syncthreads();   // all waves done reading ctr before mk overlay write
    mk[wv][0][lane] = a0; mk[wv][1][lane] = a1; mk[wv][2][lane] = a2;
    mk[wv][0][64 + lane] = e0; mk[wv][1][64 + lane] = e1; mk[wv][2][64 + lane] = e2;
    __syncthreads();
    if (t < 128) {
      double k0 = kinit, k1 = kinit, k2 = kinit;
#pragma unroll
      for (int w = 0; w < 8; ++w) {
#pragma unroll
        for (int j = 0; j < 3; ++j) {
          double key = mk[w][j][t];
          double n0 = fmin(key, k0);
          double n1 = fmin(fmax(key, k0), k1);
          double n2 = fmin(fmax(key, k1), k2);
          k0 = n0; k1 = n1; k2 = n2;
        }
      }
      float d0 = __int_as_float(__double2hiint(k0));
      float d1 = __int_as_float(__double2hiint(k1));
      float d2 = __int_as_float(__double2hiint(k2));
      float w0 = 1.f / (d0 + 1e-8f), w1 = 1.f / (d1 + 1e-8f), w2 = 1.f / (d2 + 1e-8f);
      float inv = 1.f / (w0 + w1 + w2);
      int bn = b * N_ + base + t;
      wts[bn] = w0 * inv; wts[BN_ + bn] = w1 * inv; wts[2 * BN_ + bn] = w2 * inv;
      idx[bn] = __double2loint(k0);
      idx[BN_ + bn] = __double2loint(k1);
      idx[2 * BN_ + bn] = __double2loint(k2);
    }
  } else if (bid < 704) {
    // ---- weight cast ----
    int i = (bid - 512) * 512 + t;
    if (i < 256 * CIN_) W1b[i] = (short)f2bf(W1[i]);
    if (i < 256 * 256)  W2b[i] = (short)f2bf(W2[i]);
  } else if (bid < 6848) {
    // ---- transpose+cast, two 32x32 tiles per block (12288 tiles total) ----
    int q2 = (bid - 704) * 2 + (t >> 8);
    int tt = t & 255;
    float (*tile)[33] = (float(*)[33])(smem + (t >> 8) * 4352);
    const float* in; short* outp;
    int C, Nn, RS, coff, n0, c0, b;
    if (q2 < 4096) {
      in = cf; outp = FT; C = CC_; Nn = M_; RS = CC_; coff = 0;
      n0 = (q2 & 63) * 32; c0 = ((q2 >> 6) & 7) * 32; b = q2 >> 9;
    } else {
      int q = q2 - 4096;
      in = pf; outp = x0T; C = CP_; Nn = N_; RS = CIN_; coff = 256;
      n0 = (q & 255) * 32; c0 = ((q >> 8) & 3) * 32; b = q >> 10;
    }
    const float* inb = in + (size_t)b * C * Nn;
    short* outb = outp + (size_t)b * Nn * RS;
    int tx = tt & 31, ty = tt >> 5;
#pragma unroll
    for (int i = 0; i < 32; i += 8)
      tile[ty + i][tx] = inb[(size_t)(c0 + ty + i) * Nn + n0 + tx];
    __syncthreads();
#pragma unroll
    for (int i = 0; i < 32; i += 8)
      outb[(size_t)(n0 + ty + i) * RS + coff + c0 + tx] = (short)f2bf(tile[tx][ty + i]);
  } else {
    // ---- tail: coords copy + time_emb broadcast ----
    int total = 196608 + B_ * 64 * N_;
    for (int i = (bid - 6848) * 512 + t; i < total; i += 512 * 512) {
      if (i < 196608) {
        out[16777216 + i] = pc[i];
      } else {
        int j = i - 196608;
        int bd = j >> 13;
        out[16973824 + j] = te[bd];
      }
    }
  }
}

// ---------------- gather + weighted sum -> x0T[b][n][0..256) ----------------
__global__ __launch_bounds__(256) void k_interp(
    const short* __restrict__ FT, const int* __restrict__ idx,
    const float* __restrict__ wts, short* __restrict__ x0T) {
  int b = blockIdx.y;
  int t = threadIdx.x;
  int nl = t >> 5, cch = (t & 31) * 8;
  int n = blockIdx.x * 8 + nl;
  int bn = b * N_ + n;
  int i0 = idx[bn], i1 = idx[BN_ + bn], i2 = idx[2 * BN_ + bn];
  float w0 = wts[bn], w1 = wts[BN_ + bn], w2 = wts[2 * BN_ + bn];
  const short* Fb = FT + (size_t)b * M_ * CC_;
  short8 f0 = *(const short8*)(Fb + (size_t)i0 * CC_ + cch);
  short8 f1 = *(const short8*)(Fb + (size_t)i1 * CC_ + cch);
  short8 f2 = *(const short8*)(Fb + (size_t)i2 * CC_ + cch);
  short8 r;
#pragma unroll
  for (int e = 0; e < 8; ++e) {
    float v = w0 * bf2f((unsigned short)f0[e]) + w1 * bf2f((unsigned short)f1[e]) +
              w2 * bf2f((unsigned short)f2[e]);
    r[e] = (short)f2bf(v);
  }
  *(short8*)(x0T + (size_t)bn * CIN_ + cch) = r;
}

// ---------------- bf16 MFMA GEMM, 128n x 256o tile, 8 waves, fused GN stats ----------------
// Y[b][n][o] = W[o][:] . X[b][n][:] + bias[o]; X staged ONCE (full 256-o output per block).
// part layout: [b*8+grp][64 ntiles][2]
__global__ __launch_bounds__(512) void k_gemm(
    const short* __restrict__ Wb, const short* __restrict__ Xb,
    const float* __restrict__ bias, short* __restrict__ Yb,
    float* __restrict__ part, int K) {
  __shared__ __align__(16) short sW[256 * 64];   // 32 KB
  __shared__ __align__(16) short sX[128 * 64];   // 16 KB
  int b = blockIdx.z;
  int ntile = blockIdx.y * 128;
  int t = threadIdx.x;
  int wv = t >> 6, lane = t & 63;
  int wr = wv >> 2, wc = wv & 3;      // wr: n-half (0..1), wc: o-quarter (0..3)
  int fr = lane & 15;                 // fragment row
  int g = lane >> 4;                  // k-subchunk selector
  f32x4 acc[4][4] = {};
  const short* Wp = Wb;
  const short* Xp = Xb + ((size_t)b * N_ + ntile) * K;
  for (int k0 = 0; k0 < K; k0 += 64) {
#pragma unroll
    for (int j = 0; j < 4; ++j) {     // sW: 2048 slots of 16B
      int s = j * 512 + t;
      int row = s >> 3;               // 0..255
      int kc = (s & 7) ^ (row & 7);
      gload16(Wp + (size_t)row * K + k0 + kc * 8, sW + j * 4096 + wv * 512);
    }
#pragma unroll
    for (int j = 0; j < 2; ++j) {     // sX: 1024 slots
      int s = j * 512 + t;
      int row = s >> 3;               // 0..127
      int kc = (s & 7) ^ (row & 7);
      gload16(Xp + (size_t)row * K + k0 + kc * 8, sX + j * 4096 + wv * 512);
    }
    __syncthreads();
#pragma unroll
    for (int h = 0; h < 2; ++h) {
      short8 af[4], bfr[4];
#pragma unroll
      for (int m = 0; m < 4; ++m) {
        int ra = wc * 64 + m * 16 + fr;
        af[m] = *(const short8*)(sW + ra * 64 + (((h * 4 + g) ^ (ra & 7)) << 3));
        int rb = wr * 64 + m * 16 + fr;
        bfr[m] = *(const short8*)(sX + rb * 64 + (((h * 4 + g) ^ (rb & 7)) << 3));
      }
#pragma unroll
      for (int m = 0; m < 4; ++m)
#pragma unroll
        for (int nn = 0; nn < 4; ++nn)
          acc[m][nn] = __builtin_amdgcn_mfma_f32_16x16x32_bf16(af[m], bfr[nn], acc[m][nn], 0, 0, 0);
    }
    __syncthreads();
  }
  // epilogue: store + per-lane GN partials (m<2 -> group wc*2, m>=2 -> wc*2+1)
  float s01 = 0.f, ss01 = 0.f, s23 = 0.f, ss23 = 0.f;
#pragma unroll
  for (int m = 0; m < 4; ++m) {
    int o = wc * 64 + m * 16 + g * 4;
    float4 bi = *(const float4*)(bias + o);
#pragma unroll
    for (int nn = 0; nn < 4; ++nn) {
      int n = ntile + wr * 64 + nn * 16 + fr;
      float v0 = acc[m][nn][0] + bi.x;
      float v1 = acc[m][nn][1] + bi.y;
      float v2 = acc[m][nn][2] + bi.z;
      float v3 = acc[m][nn][3] + bi.w;
      if (m < 2) { s01 += v0 + v1 + v2 + v3; ss01 += v0*v0 + v1*v1 + v2*v2 + v3*v3; }
      else       { s23 += v0 + v1 + v2 + v3; ss23 += v0*v0 + v1*v1 + v2*v2 + v3*v3; }
      short4v sv;
      sv[0] = (short)f2bf(v0);
      sv[1] = (short)f2bf(v1);
      sv[2] = (short)f2bf(v2);
      sv[3] = (short)f2bf(v3);
      *(short4v*)(Yb + ((size_t)b * N_ + n) * 256 + o) = sv;
    }
  }
#pragma unroll
  for (int off = 32; off > 0; off >>= 1) {
    s01 += __shfl_down(s01, off);
    ss01 += __shfl_down(ss01, off);
    s23 += __shfl_down(s23, off);
    ss23 += __shfl_down(ss23, off);
  }
  float* wred = (float*)sW;   // LDS reuse (k-loop done, post-barrier)
  if (lane == 0) {
    wred[wv * 4 + 0] = s01; wred[wv * 4 + 1] = ss01;
    wred[wv * 4 + 2] = s23; wred[wv * 4 + 3] = ss23;
  }
  __syncthreads();
  if (t < 16) {
    int gl = t >> 1, sel = t & 1;                 // group 0..7, sum/sumsq
    int wcq = gl >> 1;                            // which wc produced it
    int id = (gl & 1) * 2 + sel;                  // s01/ss01 vs s23/ss23
    float v = wred[(0 * 4 + wcq) * 4 + id] + wred[(1 * 4 + wcq) * 4 + id];
    part[(((size_t)b * 8 + gl) * 64 + blockIdx.y) * 2 + sel] = v;
  }
}

// ---------------- GN + swish in place (bf16 [b][n][256]), stats finalized in-block ----
__global__ __launch_bounds__(256) void k_gnapply(short* __restrict__ Y,
                                                 const float* __restrict__ part,
                                                 const float* __restrict__ gw,
                                                 const float* __restrict__ gb) {
  __shared__ float fs[128];
  int t = threadIdx.x;
  if (t < 64) {
    float s = 0.f, ss = 0.f;
    for (int j = 0; j < 64; ++j) {
      s += part[((size_t)t * 64 + j) * 2];
      ss += part[((size_t)t * 64 + j) * 2 + 1];
    }
    const float cnt = 32.f * 8192.f;
    float mean = s / cnt;
    float var = ss / cnt - mean * mean;
    fs[t * 2] = mean;
    fs[t * 2 + 1] = rsqrtf(var + 1e-5f);
  }
  __syncthreads();
  unsigned int* Yd = (unsigned int*)Y;
  int total = B_ * N_ * 128;
  for (int i = blockIdx.x * blockDim.x + t; i < total;
       i += gridDim.x * blockDim.x) {
    int o2 = i & 127;
    int b = i >> 20;
    int g = o2 >> 4;
    float mean = fs[(b * 8 + g) * 2], rstd = fs[(b * 8 + g) * 2 + 1];
    unsigned int v = Yd[i];
    int o = o2 * 2;
    float a = bf2f((unsigned short)(v & 0xFFFF));
    float c = bf2f((unsigned short)(v >> 16));
    a = (a - mean) * rstd * gw[o] + gb[o];
    c = (c - mean) * rstd * gw[o + 1] + gb[o + 1];
    a = a / (1.f + __expf(-a));
    c = c / (1.f + __expf(-c));
    Yd[i] = (unsigned int)f2bf(a) | ((unsigned int)f2bf(c) << 16);
  }
}

// ---------------- GN + swish + transpose -> out [b][o][n] f32, stats in-block ----------
__global__ __launch_bounds__(256) void k_gnapply_out(
    const short* __restrict__ Y, const float* __restrict__ part,
    const float* __restrict__ gw, const float* __restrict__ gb,
    float* __restrict__ out) {
  __shared__ float tile[64][65];
  __shared__ float fs[16];
  int b = blockIdx.z;
  int t = threadIdx.x;
  if (t < 8) {
    float s = 0.f, ss = 0.f;
    for (int j = 0; j < 64; ++j) {
      s += part[(((size_t)b * 8 + t) * 64 + j) * 2];
      ss += part[(((size_t)b * 8 + t) * 64 + j) * 2 + 1];
    }
    const float cnt = 32.f * 8192.f;
    float mean = s / cnt;
    float var = ss / cnt - mean * mean;
    fs[t * 2] = mean;
    fs[t * 2 + 1] = rsqrtf(var + 1e-5f);
  }
  __syncthreads();
  int n0 = blockIdx.x * 64, o0 = blockIdx.y * 64;
  int row = t >> 5, dcol = t & 31;
  const unsigned int* Yd = (const unsigned int*)(Y + (size_t)b * N_ * 256);
  int o = o0 + dcol * 2;
  int g = o >> 5;
  float mean = fs[g * 2], rstd = fs[g * 2 + 1];
  float w0 = gw[o], w1 = gw[o + 1], bb0 = gb[o], bb1 = gb[o + 1];
#pragma unroll
  for (int p = 0; p < 8; ++p) {
    int n = n0 + p * 8 + row;
    unsigned int v = Yd[(size_t)n * 128 + (o0 >> 1) + dcol];
    float a = bf2f((unsigned short)(v & 0xFFFF));
    float c = bf2f((unsigned short)(v >> 16));
    a = (a - mean) * rstd * w0 + bb0; a = a / (1.f + __expf(-a));
    c = (c - mean) * rstd * w1 + bb1; c = c / (1.f + __expf(-c));
    tile[p * 8 + row][dcol * 2] = a;
    tile[p * 8 + row][dcol * 2 + 1] = c;
  }
  __syncthreads();
  int ol = t >> 2, nch = (t & 3) * 16;
  float* ob = out + ((size_t)(b * 256 + o0 + ol)) * N_ + n0 + nch;
#pragma unroll
  for (int c4 = 0; c4 < 16; c4 += 4) {
    float4 v4;
    v4.x = tile[nch + c4 + 0][ol];
    v4.y = tile[nch + c4 + 1][ol];
    v4.z = tile[nch + c4 + 2][ol];
    v4.w = tile[nch + c4 + 3][ol];
    *(float4*)(ob + c4) = v4;
  }
}

extern "C" void kernel_launch(void* const* d_in, const int* in_sizes, int n_in,
                              void* d_out, int out_size, void* d_ws, size_t ws_size,
                              hipStream_t stream) {
  const float* pc  = (const float*)d_in[0];
  const float* cc  = (const float*)d_in[1];
  const float* cf  = (const float*)d_in[2];
  const float* pf  = (const float*)d_in[3];
  const float* te  = (const float*)d_in[4];
  const float* W1  = (const float*)d_in[5];
  const float* b1  = (const float*)d_in[6];
  const float* g1w = (const float*)d_in[7];
  const float* g1b = (const float*)d_in[8];
  const float* W2  = (const float*)d_in[9];
  const float* b2  = (const float*)d_in[10];
  const float* g2w = (const float*)d_in[11];
  const float* g2b = (const float*)d_in[12];
  float* out = (float*)d_out;

  char* ws = (char*)d_ws;
  size_t off = 0;
  auto alloc = [&](size_t bytes) {
    char* p = ws + off;
    off += (bytes + 255) & ~(size_t)255;
    return p;
  };
  short* FT   = (short*)alloc((size_t)B_ * M_ * CC_ * 2);       // 8.4 MB
  short* x0T  = (short*)alloc((size_t)B_ * N_ * CIN_ * 2);      // 50.3 MB
  short* y1   = (short*)alloc((size_t)B_ * N_ * 256 * 2);       // 33.6 MB
  short* W1b  = (short*)alloc(256 * 384 * 2);
  short* W2b  = (short*)alloc(256 * 256 * 2);
  int*   idx  = (int*)alloc((size_t)3 * BN_ * 4);
  float* wts  = (float*)alloc((size_t)3 * BN_ * 4);
  float* part1 = (float*)alloc(8 * 8 * 64 * 2 * 4);
  float* part2 = (float*)alloc(8 * 8 * 64 * 2 * 4);
  short* y2 = (short*)x0T;  // x0T dead after gemm1; reuse for y2

  k_front<<<7360, 512, 0, stream>>>(pc, cc, idx, wts, W1, W2, W1b, W2b,
                                    cf, FT, pf, x0T, te, out);
  k_interp<<<dim3(N_ / 8, B_), 256, 0, stream>>>(FT, idx, wts, x0T);
  k_gemm<<<dim3(1, N_ / 128, B_), 512, 0, stream>>>(W1b, x0T, b1, y1, part1, CIN_);
  k_gnapply<<<2048, 256, 0, stream>>>(y1, part1, g1w, g1b);
  k_gemm<<<dim3(1, N_ / 128, B_), 512, 0, stream>>>(W2b, y1, b2, y2, part2, 256);
  k_gnapply_out<<<dim3(N_ / 64, 4, B_), 256, 0, stream>>>(y2, part2, g2w, g2b, out);
}

// Round 13
// 165.820 us; speedup vs baseline: 1.1833x; 1.0846x over previous
//
#include <hip/hip_runtime.h>
#include <hip/hip_bf16.h>
#include <float.h>

#define B_ 8
#define N_ 8192
#define M_ 2048
#define CC_ 256
#define CP_ 128
#define CIN_ 384
#define GRP_ 8
#define BN_ (B_ * N_)

typedef __attribute__((ext_vector_type(8))) short short8;
typedef __attribute__((ext_vector_type(4))) short short4v;
typedef __attribute__((ext_vector_type(4))) float f32x4;

static __device__ __forceinline__ float bf2f(unsigned short u) {
  union { unsigned int i; float f; } v; v.i = ((unsigned int)u) << 16; return v.f;
}
static __device__ __forceinline__ unsigned short f2bf(float f) {
  union { float f; unsigned int i; } v; v.f = f;
  unsigned int u = v.i;
  unsigned int r = (u + 0x7FFFu + ((u >> 16) & 1u)) >> 16;
  return (unsigned short)r;
}
static __device__ __forceinline__ void gload16(const void* g, void* l) {
  __builtin_amdgcn_global_load_lds(
      (const __attribute__((address_space(1))) void*)g,
      (__attribute__((address_space(3))) void*)l, 16, 0, 0);
}

// ---------------- fused front: knn (512 blocks, 32KB LDS via mk-overlay) + wcast + transpose + tail
// blocks [0,512): knn | [512,704): wcast | [704,6848): transpose tiles (2/blk, 12288 tiles) | [6848,7360): tail
__global__ __launch_bounds__(512) void k_front(
    const float* __restrict__ pc, const float* __restrict__ cc,
    int* __restrict__ idx, float* __restrict__ wts,
    const float* __restrict__ W1, const float* __restrict__ W2,
    short* __restrict__ W1b, short* __restrict__ W2b,
    const float* __restrict__ cf, short* __restrict__ FT,
    const float* __restrict__ pf, short* __restrict__ x0T,
    const float* __restrict__ te, float* __restrict__ out) {
  __shared__ __align__(16) char smem[32768];
  int bid = blockIdx.x;
  int t = threadIdx.x;
  if (bid < 512) {
    // ---- 3-NN: 8 waves, 8-way M-chunks, 2 pts/thread, f64 packed keys (exact) ----
    float4* ctr = (float4*)smem;                          // 32 KB
    double (*mk)[3][128] = (double(*)[3][128])smem;       // 24 KB, overlaid after loop
    int b = bid >> 6;
    int base = (bid & 63) * 128;
    const float* ccb = cc + (size_t)b * 3 * M_;
    for (int i = t; i < M_; i += 512) {
      float x = ccb[i], y = ccb[M_ + i], z = ccb[2 * M_ + i];
      ctr[i] = make_float4(x, y, z, x * x + y * y + z * z);
    }
    __syncthreads();
    int wv = t >> 6, lane = t & 63;
    const float* pcb = pc + (size_t)b * 3 * N_;
    int na = base + lane, nb = base + 64 + lane;
    float pxa = pcb[na], pya = pcb[N_ + na], pza = pcb[2 * N_ + na];
    float pxb = pcb[nb], pyb = pcb[N_ + nb], pzb = pcb[2 * N_ + nb];
    float p2a = pxa * pxa + pya * pya + pza * pza;
    float p2b = pxb * pxb + pyb * pyb + pzb * pzb;
    const double kinit = __hiloint2double(0x7F7FFFFF, 0);
    double a0 = kinit, a1 = kinit, a2 = kinit;
    double e0 = kinit, e1 = kinit, e2 = kinit;
    const float4* C = ctr + wv * 256;
    int mbase = wv * 256;
#pragma unroll 8
    for (int m = 0; m < 256; ++m) {
      float4 c = C[m];                           // wave-uniform -> LDS broadcast
      float dota = pxa * c.x;
      dota = __builtin_fmaf(pya, c.y, dota);
      dota = __builtin_fmaf(pza, c.z, dota);
      float da = __builtin_fmaf(-2.f, dota, c.w) + p2a;
      float dotb = pxb * c.x;
      dotb = __builtin_fmaf(pyb, c.y, dotb);
      dotb = __builtin_fmaf(pzb, c.z, dotb);
      float db = __builtin_fmaf(-2.f, dotb, c.w) + p2b;
      double ka = __hiloint2double(__float_as_int(da), mbase + m);
      double kb = __hiloint2double(__float_as_int(db), mbase + m);
      double t0 = fmin(ka, a0);
      double t1 = fmin(fmax(ka, a0), a1);
      double t2 = fmin(fmax(ka, a1), a2);
      a0 = t0; a1 = t1; a2 = t2;
      double u0 = fmin(kb, e0);
      double u1 = fmin(fmax(kb, e0), e1);
      double u2 = fmin(fmax(kb, e1), e2);
      e0 = u0; e1 = u1; e2 = u2;
    }
    __syncthreads();   // all waves done reading ctr before mk overlay write
    mk[wv][0][lane] = a0; mk[wv][1][lane] = a1; mk[wv][2][lane] = a2;
    mk[wv][0][64 + lane] = e0; mk[wv][1][64 + lane] = e1; mk[wv][2][64 + lane] = e2;
    __syncthreads();
    if (t < 128) {
      double k0 = kinit, k1 = kinit, k2 = kinit;
#pragma unroll
      for (int w = 0; w < 8; ++w) {
#pragma unroll
        for (int j = 0; j < 3; ++j) {
          double key = mk[w][j][t];
          double n0 = fmin(key, k0);
          double n1 = fmin(fmax(key, k0), k1);
          double n2 = fmin(fmax(key, k1), k2);
          k0 = n0; k1 = n1; k2 = n2;
        }
      }
      float d0 = __int_as_float(__double2hiint(k0));
      float d1 = __int_as_float(__double2hiint(k1));
      float d2 = __int_as_float(__double2hiint(k2));
      float w0 = 1.f / (d0 + 1e-8f), w1 = 1.f / (d1 + 1e-8f), w2 = 1.f / (d2 + 1e-8f);
      float inv = 1.f / (w0 + w1 + w2);
      int bn = b * N_ + base + t;
      wts[bn] = w0 * inv; wts[BN_ + bn] = w1 * inv; wts[2 * BN_ + bn] = w2 * inv;
      idx[bn] = __double2loint(k0);
      idx[BN_ + bn] = __double2loint(k1);
      idx[2 * BN_ + bn] = __double2loint(k2);
    }
  } else if (bid < 704) {
    // ---- weight cast ----
    int i = (bid - 512) * 512 + t;
    if (i < 256 * CIN_) W1b[i] = (short)f2bf(W1[i]);
    if (i < 256 * 256)  W2b[i] = (short)f2bf(W2[i]);
  } else if (bid < 6848) {
    // ---- transpose+cast, two 32x32 tiles per block (12288 tiles total) ----
    int q2 = (bid - 704) * 2 + (t >> 8);
    int tt = t & 255;
    float (*tile)[33] = (float(*)[33])(smem + (t >> 8) * 4352);
    const float* in; short* outp;
    int C, Nn, RS, coff, n0, c0, b;
    if (q2 < 4096) {
      in = cf; outp = FT; C = CC_; Nn = M_; RS = CC_; coff = 0;
      n0 = (q2 & 63) * 32; c0 = ((q2 >> 6) & 7) * 32; b = q2 >> 9;
    } else {
      int q = q2 - 4096;
      in = pf; outp = x0T; C = CP_; Nn = N_; RS = CIN_; coff = 256;
      n0 = (q & 255) * 32; c0 = ((q >> 8) & 3) * 32; b = q >> 10;
    }
    const float* inb = in + (size_t)b * C * Nn;
    short* outb = outp + (size_t)b * Nn * RS;
    int tx = tt & 31, ty = tt >> 5;
#pragma unroll
    for (int i = 0; i < 32; i += 8)
      tile[ty + i][tx] = inb[(size_t)(c0 + ty + i) * Nn + n0 + tx];
    __syncthreads();
#pragma unroll
    for (int i = 0; i < 32; i += 8)
      outb[(size_t)(n0 + ty + i) * RS + coff + c0 + tx] = (short)f2bf(tile[tx][ty + i]);
  } else {
    // ---- tail: coords copy + time_emb broadcast ----
    int total = 196608 + B_ * 64 * N_;
    for (int i = (bid - 6848) * 512 + t; i < total; i += 512 * 512) {
      if (i < 196608) {
        out[16777216 + i] = pc[i];
      } else {
        int j = i - 196608;
        int bd = j >> 13;
        out[16973824 + j] = te[bd];
      }
    }
  }
}

// ---------------- gather + weighted sum -> x0T[b][n][0..256) ----------------
__global__ __launch_bounds__(256) void k_interp(
    const short* __restrict__ FT, const int* __restrict__ idx,
    const float* __restrict__ wts, short* __restrict__ x0T) {
  int b = blockIdx.y;
  int t = threadIdx.x;
  int nl = t >> 5, cch = (t & 31) * 8;
  int n = blockIdx.x * 8 + nl;
  int bn = b * N_ + n;
  int i0 = idx[bn], i1 = idx[BN_ + bn], i2 = idx[2 * BN_ + bn];
  float w0 = wts[bn], w1 = wts[BN_ + bn], w2 = wts[2 * BN_ + bn];
  const short* Fb = FT + (size_t)b * M_ * CC_;
  short8 f0 = *(const short8*)(Fb + (size_t)i0 * CC_ + cch);
  short8 f1 = *(const short8*)(Fb + (size_t)i1 * CC_ + cch);
  short8 f2 = *(const short8*)(Fb + (size_t)i2 * CC_ + cch);
  short8 r;
#pragma unroll
  for (int e = 0; e < 8; ++e) {
    float v = w0 * bf2f((unsigned short)f0[e]) + w1 * bf2f((unsigned short)f1[e]) +
              w2 * bf2f((unsigned short)f2[e]);
    r[e] = (short)f2bf(v);
  }
  *(short8*)(x0T + (size_t)bn * CIN_ + cch) = r;
}

// ---------------- bf16 MFMA GEMM, 128n x 256o tile, 8 waves, fused GN stats ----------------
// GNX=0: X staged via global_load_lds (raw). GNX=1: X reg-staged with GN+swish applied
// (using partX stats finalized per block) — replaces the separate gnapply pass.
// Y[b][n][o] = W[o][:] . X'[b][n][:] + bias[o]; part layout: [b*8+grp][64 ntiles][2]
template <int GNX>
__global__ __launch_bounds__(512) void k_gemm(
    const short* __restrict__ Wb, const short* __restrict__ Xb,
    const float* __restrict__ bias, short* __restrict__ Yb,
    float* __restrict__ part, int K,
    const float* __restrict__ partX, const float* __restrict__ gwX,
    const float* __restrict__ gbX) {
  __shared__ __align__(16) short sW[256 * 64];   // 32 KB
  __shared__ __align__(16) short sX[128 * 64];   // 16 KB
  __shared__ float4 fs2[256];                    // 4 KB (GNX param table)
  __shared__ float fsm[16];
  int b = blockIdx.z;
  int ntile = blockIdx.y * 128;
  int t = threadIdx.x;
  int wv = t >> 6, lane = t & 63;
  int wr = wv >> 2, wc = wv & 3;      // wr: n-half (0..1), wc: o-quarter (0..3)
  int fr = lane & 15;                 // fragment row
  int g = lane >> 4;                  // k-subchunk selector
  if constexpr (GNX) {
    if (t < 8) {
      float s = 0.f, ss = 0.f;
      for (int j = 0; j < 64; ++j) {
        s += partX[(((size_t)b * 8 + t) * 64 + j) * 2];
        ss += partX[(((size_t)b * 8 + t) * 64 + j) * 2 + 1];
      }
      const float cnt = 32.f * 8192.f;
      float mean = s / cnt;
      float var = ss / cnt - mean * mean;
      fsm[t * 2] = mean;
      fsm[t * 2 + 1] = rsqrtf(var + 1e-5f);
    }
    __syncthreads();
    if (t < 256) {
      int gg = t >> 5;
      fs2[t] = make_float4(fsm[gg * 2], fsm[gg * 2 + 1], gwX[t], gbX[t]);
    }
    __syncthreads();
  }
  f32x4 acc[4][4] = {};
  const short* Wp = Wb;
  const short* Xp = Xb + ((size_t)b * N_ + ntile) * K;
  for (int k0 = 0; k0 < K; k0 += 64) {
#pragma unroll
    for (int j = 0; j < 4; ++j) {     // sW: 2048 slots of 16B
      int s = j * 512 + t;
      int row = s >> 3;               // 0..255
      int kc = (s & 7) ^ (row & 7);
      gload16(Wp + (size_t)row * K + k0 + kc * 8, sW + j * 4096 + wv * 512);
    }
    if constexpr (!GNX) {
#pragma unroll
      for (int j = 0; j < 2; ++j) {   // sX: 1024 slots
        int s = j * 512 + t;
        int row = s >> 3;             // 0..127
        int kc = (s & 7) ^ (row & 7);
        gload16(Xp + (size_t)row * K + k0 + kc * 8, sX + j * 4096 + wv * 512);
      }
    } else {
      // reg-stage X with GN+swish (same global addresses as gload16 path)
      int s0 = t, s1 = 512 + t;
      int row0 = s0 >> 3, sc0 = s0 & 7, kc0 = sc0 ^ (row0 & 7);
      int row1 = s1 >> 3, sc1 = s1 & 7, kc1 = sc1 ^ (row1 & 7);
      short8 v0 = *(const short8*)(Xp + (size_t)row0 * K + k0 + kc0 * 8);
      short8 v1 = *(const short8*)(Xp + (size_t)row1 * K + k0 + kc1 * 8);
      int o0 = k0 + kc0 * 8, o1 = k0 + kc1 * 8;
      short8 r0, r1;
#pragma unroll
      for (int e = 0; e < 8; ++e) {
        float4 p = fs2[o0 + e];
        float a = bf2f((unsigned short)v0[e]);
        a = (a - p.x) * p.y * p.z + p.w;
        a = a / (1.f + __expf(-a));
        r0[e] = (short)f2bf(a);
      }
#pragma unroll
      for (int e = 0; e < 8; ++e) {
        float4 p = fs2[o1 + e];
        float a = bf2f((unsigned short)v1[e]);
        a = (a - p.x) * p.y * p.z + p.w;
        a = a / (1.f + __expf(-a));
        r1[e] = (short)f2bf(a);
      }
      *(short8*)(sX + row0 * 64 + sc0 * 8) = r0;
      *(short8*)(sX + row1 * 64 + sc1 * 8) = r1;
    }
    __syncthreads();
#pragma unroll
    for (int h = 0; h < 2; ++h) {
      short8 af[4], bfr[4];
#pragma unroll
      for (int m = 0; m < 4; ++m) {
        int ra = wc * 64 + m * 16 + fr;
        af[m] = *(const short8*)(sW + ra * 64 + (((h * 4 + g) ^ (ra & 7)) << 3));
        int rb = wr * 64 + m * 16 + fr;
        bfr[m] = *(const short8*)(sX + rb * 64 + (((h * 4 + g) ^ (rb & 7)) << 3));
      }
#pragma unroll
      for (int m = 0; m < 4; ++m)
#pragma unroll
        for (int nn = 0; nn < 4; ++nn)
          acc[m][nn] = __builtin_amdgcn_mfma_f32_16x16x32_bf16(af[m], bfr[nn], acc[m][nn], 0, 0, 0);
    }
    __syncthreads();
  }
  // epilogue: store + per-lane GN partials (m<2 -> group wc*2, m>=2 -> wc*2+1)
  float s01 = 0.f, ss01 = 0.f, s23 = 0.f, ss23 = 0.f;
#pragma unroll
  for (int m = 0; m < 4; ++m) {
    int o = wc * 64 + m * 16 + g * 4;
    float4 bi = *(const float4*)(bias + o);
#pragma unroll
    for (int nn = 0; nn < 4; ++nn) {
      int n = ntile + wr * 64 + nn * 16 + fr;
      float v0 = acc[m][nn][0] + bi.x;
      float v1 = acc[m][nn][1] + bi.y;
      float v2 = acc[m][nn][2] + bi.z;
      float v3 = acc[m][nn][3] + bi.w;
      if (m < 2) { s01 += v0 + v1 + v2 + v3; ss01 += v0*v0 + v1*v1 + v2*v2 + v3*v3; }
      else       { s23 += v0 + v1 + v2 + v3; ss23 += v0*v0 + v1*v1 + v2*v2 + v3*v3; }
      short4v sv;
      sv[0] = (short)f2bf(v0);
      sv[1] = (short)f2bf(v1);
      sv[2] = (short)f2bf(v2);
      sv[3] = (short)f2bf(v3);
      *(short4v*)(Yb + ((size_t)b * N_ + n) * 256 + o) = sv;
    }
  }
#pragma unroll
  for (int off = 32; off > 0; off >>= 1) {
    s01 += __shfl_down(s01, off);
    ss01 += __shfl_down(ss01, off);
    s23 += __shfl_down(s23, off);
    ss23 += __shfl_down(ss23, off);
  }
  float* wred = (float*)sW;   // LDS reuse (k-loop done, post-barrier)
  if (lane == 0) {
    wred[wv * 4 + 0] = s01; wred[wv * 4 + 1] = ss01;
    wred[wv * 4 + 2] = s23; wred[wv * 4 + 3] = ss23;
  }
  __syncthreads();
  if (t < 16) {
    int gl = t >> 1, sel = t & 1;                 // group 0..7, sum/sumsq
    int wcq = gl >> 1;                            // which wc produced it
    int id = (gl & 1) * 2 + sel;                  // s01/ss01 vs s23/ss23
    float v = wred[(0 * 4 + wcq) * 4 + id] + wred[(1 * 4 + wcq) * 4 + id];
    part[(((size_t)b * 8 + gl) * 64 + blockIdx.y) * 2 + sel] = v;
  }
}

// ---------------- GN + swish + transpose -> out [b][o][n] f32, stats in-block ----------
__global__ __launch_bounds__(256) void k_gnapply_out(
    const short* __restrict__ Y, const float* __restrict__ part,
    const float* __restrict__ gw, const float* __restrict__ gb,
    float* __restrict__ out) {
  __shared__ float tile[64][65];
  __shared__ float fs[16];
  int b = blockIdx.z;
  int t = threadIdx.x;
  if (t < 8) {
    float s = 0.f, ss = 0.f;
    for (int j = 0; j < 64; ++j) {
      s += part[(((size_t)b * 8 + t) * 64 + j) * 2];
      ss += part[(((size_t)b * 8 + t) * 64 + j) * 2 + 1];
    }
    const float cnt = 32.f * 8192.f;
    float mean = s / cnt;
    float var = ss / cnt - mean * mean;
    fs[t * 2] = mean;
    fs[t * 2 + 1] = rsqrtf(var + 1e-5f);
  }
  __syncthreads();
  int n0 = blockIdx.x * 64, o0 = blockIdx.y * 64;
  int row = t >> 5, dcol = t & 31;
  const unsigned int* Yd = (const unsigned int*)(Y + (size_t)b * N_ * 256);
  int o = o0 + dcol * 2;
  int g = o >> 5;
  float mean = fs[g * 2], rstd = fs[g * 2 + 1];
  float w0 = gw[o], w1 = gw[o + 1], bb0 = gb[o], bb1 = gb[o + 1];
#pragma unroll
  for (int p = 0; p < 8; ++p) {
    int n = n0 + p * 8 + row;
    unsigned int v = Yd[(size_t)n * 128 + (o0 >> 1) + dcol];
    float a = bf2f((unsigned short)(v & 0xFFFF));
    float c = bf2f((unsigned short)(v >> 16));
    a = (a - mean) * rstd * w0 + bb0; a = a / (1.f + __expf(-a));
    c = (c - mean) * rstd * w1 + bb1; c = c / (1.f + __expf(-c));
    tile[p * 8 + row][dcol * 2] = a;
    tile[p * 8 + row][dcol * 2 + 1] = c;
  }
  __syncthreads();
  int ol = t >> 2, nch = (t & 3) * 16;
  float* ob = out + ((size_t)(b * 256 + o0 + ol)) * N_ + n0 + nch;
#pragma unroll
  for (int c4 = 0; c4 < 16; c4 += 4) {
    float4 v4;
    v4.x = tile[nch + c4 + 0][ol];
    v4.y = tile[nch + c4 + 1][ol];
    v4.z = tile[nch + c4 + 2][ol];
    v4.w = tile[nch + c4 + 3][ol];
    *(float4*)(ob + c4) = v4;
  }
}

extern "C" void kernel_launch(void* const* d_in, const int* in_sizes, int n_in,
                              void* d_out, int out_size, void* d_ws, size_t ws_size,
                              hipStream_t stream) {
  const float* pc  = (const float*)d_in[0];
  const float* cc  = (const float*)d_in[1];
  const float* cf  = (const float*)d_in[2];
  const float* pf  = (const float*)d_in[3];
  const float* te  = (const float*)d_in[4];
  const float* W1  = (const float*)d_in[5];
  const float* b1  = (const float*)d_in[6];
  const float* g1w = (const float*)d_in[7];
  const float* g1b = (const float*)d_in[8];
  const float* W2  = (const float*)d_in[9];
  const float* b2  = (const float*)d_in[10];
  const float* g2w = (const float*)d_in[11];
  const float* g2b = (const float*)d_in[12];
  float* out = (float*)d_out;

  char* ws = (char*)d_ws;
  size_t off = 0;
  auto alloc = [&](size_t bytes) {
    char* p = ws + off;
    off += (bytes + 255) & ~(size_t)255;
    return p;
  };
  short* FT   = (short*)alloc((size_t)B_ * M_ * CC_ * 2);       // 8.4 MB
  short* x0T  = (short*)alloc((size_t)B_ * N_ * CIN_ * 2);      // 50.3 MB
  short* y1   = (short*)alloc((size_t)B_ * N_ * 256 * 2);       // 33.6 MB
  short* W1b  = (short*)alloc(256 * 384 * 2);
  short* W2b  = (short*)alloc(256 * 256 * 2);
  int*   idx  = (int*)alloc((size_t)3 * BN_ * 4);
  float* wts  = (float*)alloc((size_t)3 * BN_ * 4);
  float* part1 = (float*)alloc(8 * 8 * 64 * 2 * 4);
  float* part2 = (float*)alloc(8 * 8 * 64 * 2 * 4);
  short* y2 = (short*)x0T;  // x0T dead after gemm1; reuse for y2

  k_front<<<7360, 512, 0, stream>>>(pc, cc, idx, wts, W1, W2, W1b, W2b,
                                    cf, FT, pf, x0T, te, out);
  k_interp<<<dim3(N_ / 8, B_), 256, 0, stream>>>(FT, idx, wts, x0T);
  k_gemm<0><<<dim3(1, N_ / 128, B_), 512, 0, stream>>>(
      W1b, x0T, b1, y1, part1, CIN_, nullptr, nullptr, nullptr);
  k_gemm<1><<<dim3(1, N_ / 128, B_), 512, 0, stream>>>(
      W2b, y1, b2, y2, part2, 256, part1, g1w, g1b);
  k_gnapply_out<<<dim3(N_ / 64, 4, B_), 256, 0, stream>>>(y2, part2, g2w, g2b, out);
}